// Round 15
// baseline (2338.267 us; speedup 1.0000x reference)
//
#include <hip/hip_runtime.h>
#include <hip/hip_fp16.h>

#define TT 1024
#define BB 128
#define II 256
#define HH 256
#define NG 768   // 3*H

// Static scratch: x bf16, wih^T bf16, gi f16 (bias folded in).
__device__ __align__(16) unsigned short g_xbf[(size_t)TT * BB * II];   // 67 MB
__device__ __align__(16) unsigned short g_wihB[NG * II];               // 384 KB
__device__ __align__(16) _Float16       g_gi[(size_t)TT * BB * NG];    // 201 MB

typedef __attribute__((ext_vector_type(8))) short    bfrag;
typedef __attribute__((ext_vector_type(8))) _Float16 hfrag;
typedef __attribute__((ext_vector_type(4))) float    f32x4;

__device__ __forceinline__ unsigned short f2bf(float f) {
    unsigned u = __float_as_uint(f);
    return (unsigned short)((u + 0x7fffu + ((u >> 16) & 1u)) >> 16);   // RNE
}

// ---------------- phase 1a: x f32 -> bf16 ----------------
__global__ void cvt_x_kernel(const float* __restrict__ x) {
    const int n4 = TT * BB * II / 4;
    for (int i = blockIdx.x * blockDim.x + threadIdx.x; i < n4;
         i += gridDim.x * blockDim.x) {
        float4 v = reinterpret_cast<const float4*>(x)[i];
        ushort4 o;
        o.x = f2bf(v.x); o.y = f2bf(v.y); o.z = f2bf(v.z); o.w = f2bf(v.w);
        reinterpret_cast<ushort4*>(g_xbf)[i] = o;
    }
}

// ---------------- phase 1b: wihT [k][n] -> wihB [n][k] bf16 ----------------
__global__ void cvt_wih_kernel(const float* __restrict__ wihT) {
    const int n = blockIdx.x;
    const int k = threadIdx.x;
    g_wihB[n * II + k] = f2bf(wihT[k * NG + n]);
}

// ---------------- phase 2: gi = x @ wihT + bias (MFMA bf16, f16 out) ----------------
__global__ void __launch_bounds__(256) gi_gemm_kernel(const float* __restrict__ bias) {
    __shared__ unsigned short Ab[128 * 32];
    __shared__ unsigned short Bb[128 * 32];
    const int tid = threadIdx.x;
    const int mt = blockIdx.x / 6, nt = blockIdx.x % 6;
    const int m0 = mt * 128, n0 = nt * 128;
    const int l = tid & 63, w = tid >> 6;
    const int wr = w >> 1, wc = w & 1;
    const int srow = tid >> 2, scol = (tid & 3) * 8;

    f32x4 acc[4][4] = {};

    for (int ks = 0; ks < 8; ++ks) {
        const int k0 = ks * 32;
        __syncthreads();
        #pragma unroll
        for (int c = 0; c < 2; ++c) {
            const int row = c * 64 + srow;
            *reinterpret_cast<uint4*>(&Ab[row * 32 + scol]) =
                *reinterpret_cast<const uint4*>(&g_xbf[(size_t)(m0 + row) * II + k0 + scol]);
            *reinterpret_cast<uint4*>(&Bb[row * 32 + scol]) =
                *reinterpret_cast<const uint4*>(&g_wihB[(n0 + row) * II + k0 + scol]);
        }
        __syncthreads();
        bfrag af[4], bf[4];
        #pragma unroll
        for (int i = 0; i < 4; ++i) {
            af[i] = *reinterpret_cast<const bfrag*>(
                        &Ab[(wr * 64 + i * 16 + (l & 15)) * 32 + (l >> 4) * 8]);
            bf[i] = *reinterpret_cast<const bfrag*>(
                        &Bb[(wc * 64 + i * 16 + (l & 15)) * 32 + (l >> 4) * 8]);
        }
        #pragma unroll
        for (int mi = 0; mi < 4; ++mi)
            #pragma unroll
            for (int ni = 0; ni < 4; ++ni)
                acc[mi][ni] = __builtin_amdgcn_mfma_f32_16x16x32_bf16(
                                  af[mi], bf[ni], acc[mi][ni], 0, 0, 0);
    }
    #pragma unroll
    for (int mi = 0; mi < 4; ++mi) {
        const int grow = m0 + wr * 64 + mi * 16 + (l >> 4) * 4;
        #pragma unroll
        for (int ni = 0; ni < 4; ++ni) {
            const int gcol = n0 + wc * 64 + ni * 16 + (l & 15);
            const float bv = bias[gcol];
            #pragma unroll
            for (int q = 0; q < 4; ++q)
                g_gi[(size_t)(grow + q) * NG + gcol] = (_Float16)(acc[mi][ni][q] + bv);
        }
    }
}

// ---------------- phase 3: recurrence, whh ENTIRELY register-resident ----------------
// 128 WGs (one batch row) x 256 threads (4 waves, 1/SIMD). Register law
// (r2-r14): arch-VGPR cap = 512KB/(2WG x thr x 4B) -> 256 at 256 threads;
// asm "+a" pins allocate AGPRs beyond that (r11) up to another 256.
// Wave w owns col-tiles {4w..4w+3} per gate = 96 B-frags = 384 words/lane:
//   r,z gates (64 frags, 256 words) -> AGPR via asm("" : "+a") pin;
//   n gate    (32 frags, 128 words) -> arch VGPR SSA.
// Per step: 8 broadcast ds_read_b128 of h (A = row-0-only, r8-proven) +
// 96 builtin MFMAs (hazards compiler-managed; r10's hand-asm corrupted) +
// lane-local epilogue (lanes 0-15 own j = (4w+i)*16+ln15 for i=0..3, all
// three gates local) -> ONE barrier/step. Zero per-step weight memory.
#define MF(A, B, C) __builtin_amdgcn_mfma_f32_16x16x32_f16((A), (B), (C), 0, 0, 0)

#define LDB1(NAME, GATE, TB, KT)                                            \
    hfrag NAME;                                                             \
    _Pragma("unroll")                                                       \
    for (int e = 0; e < 8; ++e)                                             \
        NAME[e] = (_Float16)whhT[(size_t)((KT) * 32 + g8 + e) * NG          \
                                 + (GATE) * HH + (TB) + ln15];

#define DECL8(P, GATE, I, TB)                                               \
    LDB1(P##I##_0, GATE, TB, 0) LDB1(P##I##_1, GATE, TB, 1)                 \
    LDB1(P##I##_2, GATE, TB, 2) LDB1(P##I##_3, GATE, TB, 3)                 \
    LDB1(P##I##_4, GATE, TB, 4) LDB1(P##I##_5, GATE, TB, 5)                 \
    LDB1(P##I##_6, GATE, TB, 6) LDB1(P##I##_7, GATE, TB, 7)

#define PIN8(P, I)                                                          \
    asm("" : "+a"(P##I##_0)); asm("" : "+a"(P##I##_1));                     \
    asm("" : "+a"(P##I##_2)); asm("" : "+a"(P##I##_3));                     \
    asm("" : "+a"(P##I##_4)); asm("" : "+a"(P##I##_5));                     \
    asm("" : "+a"(P##I##_6)); asm("" : "+a"(P##I##_7));

#define KST(KT)                                                             \
    {                                                                       \
        const hfrag Av = *reinterpret_cast<const hfrag*>(hl + (KT) * 32 + g8); \
        const hfrag A  = (ln15 == 0) ? Av : hz;                             \
        aR0 = MF(A, BR0_##KT, aR0); aR1 = MF(A, BR1_##KT, aR1);             \
        aR2 = MF(A, BR2_##KT, aR2); aR3 = MF(A, BR3_##KT, aR3);             \
        aZ0 = MF(A, BZ0_##KT, aZ0); aZ1 = MF(A, BZ1_##KT, aZ1);             \
        aZ2 = MF(A, BZ2_##KT, aZ2); aZ3 = MF(A, BZ3_##KT, aZ3);             \
        aN0 = MF(A, BN0_##KT, aN0); aN1 = MF(A, BN1_##KT, aN1);             \
        aN2 = MF(A, BN2_##KT, aN2); aN3 = MF(A, BN3_##KT, aN3);             \
    }

__global__ void __launch_bounds__(256, 1) gru_rec_kernel(
    const float* __restrict__ h0, const float* __restrict__ whhT,
    float* __restrict__ out)
{
    __shared__ __align__(16) _Float16 hbuf[2][HH];   // 1 KB ping-pong h (f16)

    const int t    = threadIdx.x;
    const int b    = blockIdx.x;
    const int w    = t >> 6;            // wave 0..3
    const int l    = t & 63;
    const int ln15 = l & 15;
    const int g8   = (l >> 4) * 8;      // k-sub-chunk base
    const int tb0  = (4 * w + 0) * 16, tb1 = (4 * w + 1) * 16;
    const int tb2  = (4 * w + 2) * 16, tb3 = (4 * w + 3) * 16;
    const int j0 = tb0 + ln15, j1 = tb1 + ln15, j2 = tb2 + ln15, j3 = tb3 + ln15;

    // --- 96 whh B-fragments: r,z pinned to AGPR; n in arch VGPRs ---
    DECL8(BR, 0, 0, tb0) PIN8(BR, 0)  DECL8(BR, 0, 1, tb1) PIN8(BR, 1)
    DECL8(BR, 0, 2, tb2) PIN8(BR, 2)  DECL8(BR, 0, 3, tb3) PIN8(BR, 3)
    DECL8(BZ, 1, 0, tb0) PIN8(BZ, 0)  DECL8(BZ, 1, 1, tb1) PIN8(BZ, 1)
    DECL8(BZ, 1, 2, tb2) PIN8(BZ, 2)  DECL8(BZ, 1, 3, tb3) PIN8(BZ, 3)
    DECL8(BN, 2, 0, tb0)              DECL8(BN, 2, 1, tb1)
    DECL8(BN, 2, 2, tb2)              DECL8(BN, 2, 3, tb3)

    const hfrag hz = {};
    const int gq = l >> 4;              // 0 => epilogue lane

    // --- init h ---
    float hp0 = h0[b * HH + j0], hp1 = h0[b * HH + j1];
    float hp2 = h0[b * HH + j2], hp3 = h0[b * HH + j3];
    hbuf[0][t] = (_Float16)h0[b * HH + t];
    __syncthreads();

    // gi (bias pre-folded) primed for t=0 on epilogue lanes
    float gR0 = 0.f, gR1 = 0.f, gR2 = 0.f, gR3 = 0.f;
    float gZ0 = 0.f, gZ1 = 0.f, gZ2 = 0.f, gZ3 = 0.f;
    float gN0 = 0.f, gN1 = 0.f, gN2 = 0.f, gN3 = 0.f;
    if (gq == 0) {
        const _Float16* gb = g_gi + (size_t)b * NG;
        gR0 = (float)gb[j0]; gR1 = (float)gb[j1]; gR2 = (float)gb[j2]; gR3 = (float)gb[j3];
        gZ0 = (float)gb[256 + j0]; gZ1 = (float)gb[256 + j1];
        gZ2 = (float)gb[256 + j2]; gZ3 = (float)gb[256 + j3];
        gN0 = (float)gb[512 + j0]; gN1 = (float)gb[512 + j1];
        gN2 = (float)gb[512 + j2]; gN3 = (float)gb[512 + j3];
    }

    for (int ts = 0; ts < TT; ++ts) {
        const _Float16* hl  = hbuf[ts & 1];
        _Float16*       hn_ = hbuf[(ts & 1) ^ 1];

        // prefetch gi[ts+1]
        float nR0 = gR0, nR1 = gR1, nR2 = gR2, nR3 = gR3;
        float nZ0 = gZ0, nZ1 = gZ1, nZ2 = gZ2, nZ3 = gZ3;
        float nN0 = gN0, nN1 = gN1, nN2 = gN2, nN3 = gN3;
        if (gq == 0 && ts + 1 < TT) {
            const _Float16* gn = g_gi + ((size_t)(ts + 1) * BB + b) * NG;
            nR0 = (float)gn[j0]; nR1 = (float)gn[j1]; nR2 = (float)gn[j2]; nR3 = (float)gn[j3];
            nZ0 = (float)gn[256 + j0]; nZ1 = (float)gn[256 + j1];
            nZ2 = (float)gn[256 + j2]; nZ3 = (float)gn[256 + j3];
            nN0 = (float)gn[512 + j0]; nN1 = (float)gn[512 + j1];
            nN2 = (float)gn[512 + j2]; nN3 = (float)gn[512 + j3];
        }

        f32x4 aR0 = {0.f,0.f,0.f,0.f}, aR1 = {0.f,0.f,0.f,0.f};
        f32x4 aR2 = {0.f,0.f,0.f,0.f}, aR3 = {0.f,0.f,0.f,0.f};
        f32x4 aZ0 = {0.f,0.f,0.f,0.f}, aZ1 = {0.f,0.f,0.f,0.f};
        f32x4 aZ2 = {0.f,0.f,0.f,0.f}, aZ3 = {0.f,0.f,0.f,0.f};
        f32x4 aN0 = {0.f,0.f,0.f,0.f}, aN1 = {0.f,0.f,0.f,0.f};
        f32x4 aN2 = {0.f,0.f,0.f,0.f}, aN3 = {0.f,0.f,0.f,0.f};
        KST(0) KST(1) KST(2) KST(3) KST(4) KST(5) KST(6) KST(7)

        // epilogue: C row 0 = acc[0] on lanes gq==0 (col = ln15)
        const float r0 = 1.f / (1.f + __expf(-(aR0[0] + gR0)));
        const float z0 = 1.f / (1.f + __expf(-(aZ0[0] + gZ0)));
        const float e0 = __expf(2.f * (gN0 + r0 * aN0[0]));
        const float hv0 = (1.f - z0) * (1.f - 2.f / (e0 + 1.f)) + z0 * hp0;

        const float r1 = 1.f / (1.f + __expf(-(aR1[0] + gR1)));
        const float z1 = 1.f / (1.f + __expf(-(aZ1[0] + gZ1)));
        const float e1 = __expf(2.f * (gN1 + r1 * aN1[0]));
        const float hv1 = (1.f - z1) * (1.f - 2.f / (e1 + 1.f)) + z1 * hp1;

        const float r2 = 1.f / (1.f + __expf(-(aR2[0] + gR2)));
        const float z2 = 1.f / (1.f + __expf(-(aZ2[0] + gZ2)));
        const float e2 = __expf(2.f * (gN2 + r2 * aN2[0]));
        const float hv2 = (1.f - z2) * (1.f - 2.f / (e2 + 1.f)) + z2 * hp2;

        const float r3 = 1.f / (1.f + __expf(-(aR3[0] + gR3)));
        const float z3 = 1.f / (1.f + __expf(-(aZ3[0] + gZ3)));
        const float e3 = __expf(2.f * (gN3 + r3 * aN3[0]));
        const float hv3 = (1.f - z3) * (1.f - 2.f / (e3 + 1.f)) + z3 * hp3;

        if (gq == 0) {
            hp0 = hv0; hp1 = hv1; hp2 = hv2; hp3 = hv3;
            hn_[j0] = (_Float16)hv0; hn_[j1] = (_Float16)hv1;
            hn_[j2] = (_Float16)hv2; hn_[j3] = (_Float16)hv3;
            if (ts == TT - 1) {
                out[b * HH + j0] = hv0; out[b * HH + j1] = hv1;
                out[b * HH + j2] = hv2; out[b * HH + j3] = hv3;
            }
        }

        gR0 = nR0; gR1 = nR1; gR2 = nR2; gR3 = nR3;
        gZ0 = nZ0; gZ1 = nZ1; gZ2 = nZ2; gZ3 = nZ3;
        gN0 = nN0; gN1 = nN1; gN2 = nN2; gN3 = nN3;
        __syncthreads();
    }
}

extern "C" void kernel_launch(void* const* d_in, const int* in_sizes, int n_in,
                              void* d_out, int out_size, void* d_ws, size_t ws_size,
                              hipStream_t stream) {
    const float* x    = (const float*)d_in[0];
    const float* h0   = (const float*)d_in[1];
    const float* wihT = (const float*)d_in[2];
    const float* whhT = (const float*)d_in[3];
    const float* bias = (const float*)d_in[4];
    float*       out  = (float*)d_out;

    cvt_x_kernel<<<2048, 256, 0, stream>>>(x);
    cvt_wih_kernel<<<NG, 256, 0, stream>>>(wihT);
    gi_gemm_kernel<<<1024 * 6, 256, 0, stream>>>(bias);
    gru_rec_kernel<<<BB, 256, 0, stream>>>(h0, whhT, out);
}

// Round 16
// 1477.837 us; speedup vs baseline: 1.5822x; 1.5822x over previous
//
#include <hip/hip_runtime.h>
#include <hip/hip_fp16.h>

#define TT 1024
#define BB 128
#define II 256
#define HH 256
#define NG 768   // 3*H

// Static scratch: x bf16, wih^T bf16, gi f16 (bias folded in).
__device__ __align__(16) unsigned short g_xbf[(size_t)TT * BB * II];   // 67 MB
__device__ __align__(16) unsigned short g_wihB[NG * II];               // 384 KB
__device__ __align__(16) _Float16       g_gi[(size_t)TT * BB * NG];    // 201 MB

typedef __attribute__((ext_vector_type(8))) short    bfrag;
typedef __attribute__((ext_vector_type(8))) _Float16 hfrag;
typedef __attribute__((ext_vector_type(4))) float    f32x4;

__device__ __forceinline__ unsigned short f2bf(float f) {
    unsigned u = __float_as_uint(f);
    return (unsigned short)((u + 0x7fffu + ((u >> 16) & 1u)) >> 16);   // RNE
}

// ---------------- phase 1a: x f32 -> bf16 ----------------
__global__ void cvt_x_kernel(const float* __restrict__ x) {
    const int n4 = TT * BB * II / 4;
    for (int i = blockIdx.x * blockDim.x + threadIdx.x; i < n4;
         i += gridDim.x * blockDim.x) {
        float4 v = reinterpret_cast<const float4*>(x)[i];
        ushort4 o;
        o.x = f2bf(v.x); o.y = f2bf(v.y); o.z = f2bf(v.z); o.w = f2bf(v.w);
        reinterpret_cast<ushort4*>(g_xbf)[i] = o;
    }
}

// ---------------- phase 1b: wihT [k][n] -> wihB [n][k] bf16 ----------------
__global__ void cvt_wih_kernel(const float* __restrict__ wihT) {
    const int n = blockIdx.x;
    const int k = threadIdx.x;
    g_wihB[n * II + k] = f2bf(wihT[k * NG + n]);
}

// ---------------- phase 2: gi = x @ wihT + bias (MFMA bf16, f16 out) ----------------
__global__ void __launch_bounds__(256) gi_gemm_kernel(const float* __restrict__ bias) {
    __shared__ unsigned short Ab[128 * 32];
    __shared__ unsigned short Bb[128 * 32];
    const int tid = threadIdx.x;
    const int mt = blockIdx.x / 6, nt = blockIdx.x % 6;
    const int m0 = mt * 128, n0 = nt * 128;
    const int l = tid & 63, w = tid >> 6;
    const int wr = w >> 1, wc = w & 1;
    const int srow = tid >> 2, scol = (tid & 3) * 8;

    f32x4 acc[4][4] = {};

    for (int ks = 0; ks < 8; ++ks) {
        const int k0 = ks * 32;
        __syncthreads();
        #pragma unroll
        for (int c = 0; c < 2; ++c) {
            const int row = c * 64 + srow;
            *reinterpret_cast<uint4*>(&Ab[row * 32 + scol]) =
                *reinterpret_cast<const uint4*>(&g_xbf[(size_t)(m0 + row) * II + k0 + scol]);
            *reinterpret_cast<uint4*>(&Bb[row * 32 + scol]) =
                *reinterpret_cast<const uint4*>(&g_wihB[(n0 + row) * II + k0 + scol]);
        }
        __syncthreads();
        bfrag af[4], bf[4];
        #pragma unroll
        for (int i = 0; i < 4; ++i) {
            af[i] = *reinterpret_cast<const bfrag*>(
                        &Ab[(wr * 64 + i * 16 + (l & 15)) * 32 + (l >> 4) * 8]);
            bf[i] = *reinterpret_cast<const bfrag*>(
                        &Bb[(wc * 64 + i * 16 + (l & 15)) * 32 + (l >> 4) * 8]);
        }
        #pragma unroll
        for (int mi = 0; mi < 4; ++mi)
            #pragma unroll
            for (int ni = 0; ni < 4; ++ni)
                acc[mi][ni] = __builtin_amdgcn_mfma_f32_16x16x32_bf16(
                                  af[mi], bf[ni], acc[mi][ni], 0, 0, 0);
    }
    #pragma unroll
    for (int mi = 0; mi < 4; ++mi) {
        const int grow = m0 + wr * 64 + mi * 16 + (l >> 4) * 4;
        #pragma unroll
        for (int ni = 0; ni < 4; ++ni) {
            const int gcol = n0 + wc * 64 + ni * 16 + (l & 15);
            const float bv = bias[gcol];
            #pragma unroll
            for (int q = 0; q < 4; ++q)
                g_gi[(size_t)(grow + q) * NG + gcol] = (_Float16)(acc[mi][ni][q] + bv);
        }
    }
}

// ---------------- phase 3: recurrence, whh fully AGPR-resident ----------------
// 128 WGs (one batch row) x 256 threads (4 waves, 1 wave/SIMD, 512 unified
// regs/lane). r15 lesson: AGPR capacity = 512 - accum_offset, and
// accum_offset inflates to the UNPINNED arch demand -- so pin ALL 96
// B-frags (384 words) to AGPR and keep arch demand ~110:
//  - no A-zeroing (C row 0 depends only on A row 0; rows 1-15 hold
//    duplicate h values and corrupt only unread C rows) -> no hz, no
//    cndmask per KST;
//  - thread t owns output column j == t (wave w, group gq, lane ln15 ->
//    j = w*64 + gq*16 + ln15 = t): gi loads coalesced, loaded at loop top
//    (latency hides under the 96-MFMA block), acc picked by 9 cndmasks.
// One barrier per step; zero per-step weight memory traffic.
#define MF(A, B, C) __builtin_amdgcn_mfma_f32_16x16x32_f16((A), (B), (C), 0, 0, 0)

#define LDB1(NAME, GATE, TB, KT)                                            \
    hfrag NAME;                                                             \
    _Pragma("unroll")                                                       \
    for (int e = 0; e < 8; ++e)                                             \
        NAME[e] = (_Float16)whhT[(size_t)((KT) * 32 + g8 + e) * NG          \
                                 + (GATE) * HH + (TB) + ln15];              \
    asm("" : "+a"(NAME));

#define DECL8(P, GATE, I, TB)                                               \
    LDB1(P##I##_0, GATE, TB, 0) LDB1(P##I##_1, GATE, TB, 1)                 \
    LDB1(P##I##_2, GATE, TB, 2) LDB1(P##I##_3, GATE, TB, 3)                 \
    LDB1(P##I##_4, GATE, TB, 4) LDB1(P##I##_5, GATE, TB, 5)                 \
    LDB1(P##I##_6, GATE, TB, 6) LDB1(P##I##_7, GATE, TB, 7)

#define KST(KT)                                                             \
    {                                                                       \
        const hfrag A = *reinterpret_cast<const hfrag*>(hl + (KT) * 32 + g8); \
        aR0 = MF(A, BR0_##KT, aR0); aR1 = MF(A, BR1_##KT, aR1);             \
        aR2 = MF(A, BR2_##KT, aR2); aR3 = MF(A, BR3_##KT, aR3);             \
        aZ0 = MF(A, BZ0_##KT, aZ0); aZ1 = MF(A, BZ1_##KT, aZ1);             \
        aZ2 = MF(A, BZ2_##KT, aZ2); aZ3 = MF(A, BZ3_##KT, aZ3);             \
        aN0 = MF(A, BN0_##KT, aN0); aN1 = MF(A, BN1_##KT, aN1);             \
        aN2 = MF(A, BN2_##KT, aN2); aN3 = MF(A, BN3_##KT, aN3);             \
    }

__global__ void __launch_bounds__(256, 1)
__attribute__((amdgpu_waves_per_eu(1, 1)))
gru_rec_kernel(
    const float* __restrict__ h0, const float* __restrict__ whhT,
    float* __restrict__ out)
{
    __shared__ __align__(16) _Float16 hbuf[2][HH];   // 1 KB ping-pong h (f16)

    const int t    = threadIdx.x;
    const int b    = blockIdx.x;
    const int w    = t >> 6;            // wave 0..3
    const int l    = t & 63;
    const int ln15 = l & 15;
    const int gq   = l >> 4;            // lane's tile-group 0..3
    const int g8   = gq * 8;            // k-sub-chunk base
    const int tb0  = (4 * w + 0) * 16, tb1 = (4 * w + 1) * 16;
    const int tb2  = (4 * w + 2) * 16, tb3 = (4 * w + 3) * 16;
    // thread t's own output column: j = w*64 + gq*16 + ln15 == t

    // --- 96 whh B-fragments, ALL pinned to AGPR ---
    DECL8(BR, 0, 0, tb0) DECL8(BR, 0, 1, tb1)
    DECL8(BR, 0, 2, tb2) DECL8(BR, 0, 3, tb3)
    DECL8(BZ, 1, 0, tb0) DECL8(BZ, 1, 1, tb1)
    DECL8(BZ, 1, 2, tb2) DECL8(BZ, 1, 3, tb3)
    DECL8(BN, 2, 0, tb0) DECL8(BN, 2, 1, tb1)
    DECL8(BN, 2, 2, tb2) DECL8(BN, 2, 3, tb3)

    // --- init h: thread t owns column t ---
    float hp = h0[b * HH + t];
    hbuf[0][t] = (_Float16)hp;
    __syncthreads();

    for (int ts = 0; ts < TT; ++ts) {
        const _Float16* hl  = hbuf[ts & 1];
        _Float16*       hn_ = hbuf[(ts & 1) ^ 1];

        // gi for this step (coalesced, L3-resident; hides under MFMAs)
        const _Float16* gb = g_gi + ((size_t)ts * BB + b) * NG + t;
        const float gR = (float)gb[0];
        const float gZ = (float)gb[256];
        const float gN = (float)gb[512];

        f32x4 aR0 = {0.f,0.f,0.f,0.f}, aR1 = {0.f,0.f,0.f,0.f};
        f32x4 aR2 = {0.f,0.f,0.f,0.f}, aR3 = {0.f,0.f,0.f,0.f};
        f32x4 aZ0 = {0.f,0.f,0.f,0.f}, aZ1 = {0.f,0.f,0.f,0.f};
        f32x4 aZ2 = {0.f,0.f,0.f,0.f}, aZ3 = {0.f,0.f,0.f,0.f};
        f32x4 aN0 = {0.f,0.f,0.f,0.f}, aN1 = {0.f,0.f,0.f,0.f};
        f32x4 aN2 = {0.f,0.f,0.f,0.f}, aN3 = {0.f,0.f,0.f,0.f};
        KST(0) KST(1) KST(2) KST(3) KST(4) KST(5) KST(6) KST(7)

        // all C rows are equal (A rows duplicated), so every lane's acc[0]
        // holds gh for col ln15 of its tile; pick this lane's tile by gq.
        const float sR = gq == 0 ? aR0[0] : gq == 1 ? aR1[0] : gq == 2 ? aR2[0] : aR3[0];
        const float sZ = gq == 0 ? aZ0[0] : gq == 1 ? aZ1[0] : gq == 2 ? aZ2[0] : aZ3[0];
        const float sN = gq == 0 ? aN0[0] : gq == 1 ? aN1[0] : gq == 2 ? aN2[0] : aN3[0];

        const float r  = 1.f / (1.f + __expf(-(sR + gR)));
        const float z  = 1.f / (1.f + __expf(-(sZ + gZ)));
        const float e  = __expf(2.f * (gN + r * sN));   // tanh
        const float n  = 1.f - 2.f / (e + 1.f);
        const float hv = (1.f - z) * n + z * hp;

        hp = hv;
        hn_[t] = (_Float16)hv;
        if (ts == TT - 1) out[b * HH + t] = hv;
        __syncthreads();
    }
}

extern "C" void kernel_launch(void* const* d_in, const int* in_sizes, int n_in,
                              void* d_out, int out_size, void* d_ws, size_t ws_size,
                              hipStream_t stream) {
    const float* x    = (const float*)d_in[0];
    const float* h0   = (const float*)d_in[1];
    const float* wihT = (const float*)d_in[2];
    const float* whhT = (const float*)d_in[3];
    const float* bias = (const float*)d_in[4];
    float*       out  = (float*)d_out;

    cvt_x_kernel<<<2048, 256, 0, stream>>>(x);
    cvt_wih_kernel<<<NG, 256, 0, stream>>>(wihT);
    gi_gemm_kernel<<<1024 * 6, 256, 0, stream>>>(bias);
    gru_rec_kernel<<<BB, 256, 0, stream>>>(h0, whhT, out);
}

// Round 17
// 1345.375 us; speedup vs baseline: 1.7380x; 1.0985x over previous
//
#include <hip/hip_runtime.h>
#include <hip/hip_fp16.h>

#define TT 1024
#define BB 128
#define II 256
#define HH 256
#define NG 768   // 3*H

// Static scratch: x bf16, wih^T bf16, gi f16 (bias folded in).
__device__ __align__(16) unsigned short g_xbf[(size_t)TT * BB * II];   // 67 MB
__device__ __align__(16) unsigned short g_wihB[NG * II];               // 384 KB
__device__ __align__(16) _Float16       g_gi[(size_t)TT * BB * NG];    // 201 MB

typedef __attribute__((ext_vector_type(8))) short    bfrag;
typedef __attribute__((ext_vector_type(8))) _Float16 hfrag;
typedef __attribute__((ext_vector_type(4))) float    f32x4;

__device__ __forceinline__ unsigned short f2bf(float f) {
    unsigned u = __float_as_uint(f);
    return (unsigned short)((u + 0x7fffu + ((u >> 16) & 1u)) >> 16);   // RNE
}

// ---------------- phase 1a: x f32 -> bf16 ----------------
__global__ void cvt_x_kernel(const float* __restrict__ x) {
    const int n4 = TT * BB * II / 4;
    for (int i = blockIdx.x * blockDim.x + threadIdx.x; i < n4;
         i += gridDim.x * blockDim.x) {
        float4 v = reinterpret_cast<const float4*>(x)[i];
        ushort4 o;
        o.x = f2bf(v.x); o.y = f2bf(v.y); o.z = f2bf(v.z); o.w = f2bf(v.w);
        reinterpret_cast<ushort4*>(g_xbf)[i] = o;
    }
}

// ---------------- phase 1b: wihT [k][n] -> wihB [n][k] bf16 ----------------
__global__ void cvt_wih_kernel(const float* __restrict__ wihT) {
    const int n = blockIdx.x;
    const int k = threadIdx.x;
    g_wihB[n * II + k] = f2bf(wihT[k * NG + n]);
}

// ---------------- phase 2: gi = x @ wihT + bias (MFMA bf16, f16 out) ----------------
__global__ void __launch_bounds__(256) gi_gemm_kernel(const float* __restrict__ bias) {
    __shared__ unsigned short Ab[128 * 32];
    __shared__ unsigned short Bb[128 * 32];
    const int tid = threadIdx.x;
    const int mt = blockIdx.x / 6, nt = blockIdx.x % 6;
    const int m0 = mt * 128, n0 = nt * 128;
    const int l = tid & 63, w = tid >> 6;
    const int wr = w >> 1, wc = w & 1;
    const int srow = tid >> 2, scol = (tid & 3) * 8;

    f32x4 acc[4][4] = {};

    for (int ks = 0; ks < 8; ++ks) {
        const int k0 = ks * 32;
        __syncthreads();
        #pragma unroll
        for (int c = 0; c < 2; ++c) {
            const int row = c * 64 + srow;
            *reinterpret_cast<uint4*>(&Ab[row * 32 + scol]) =
                *reinterpret_cast<const uint4*>(&g_xbf[(size_t)(m0 + row) * II + k0 + scol]);
            *reinterpret_cast<uint4*>(&Bb[row * 32 + scol]) =
                *reinterpret_cast<const uint4*>(&g_wihB[(n0 + row) * II + k0 + scol]);
        }
        __syncthreads();
        bfrag af[4], bf[4];
        #pragma unroll
        for (int i = 0; i < 4; ++i) {
            af[i] = *reinterpret_cast<const bfrag*>(
                        &Ab[(wr * 64 + i * 16 + (l & 15)) * 32 + (l >> 4) * 8]);
            bf[i] = *reinterpret_cast<const bfrag*>(
                        &Bb[(wc * 64 + i * 16 + (l & 15)) * 32 + (l >> 4) * 8]);
        }
        #pragma unroll
        for (int mi = 0; mi < 4; ++mi)
            #pragma unroll
            for (int ni = 0; ni < 4; ++ni)
                acc[mi][ni] = __builtin_amdgcn_mfma_f32_16x16x32_bf16(
                                  af[mi], bf[ni], acc[mi][ni], 0, 0, 0);
    }
    #pragma unroll
    for (int mi = 0; mi < 4; ++mi) {
        const int grow = m0 + wr * 64 + mi * 16 + (l >> 4) * 4;
        #pragma unroll
        for (int ni = 0; ni < 4; ++ni) {
            const int gcol = n0 + wc * 64 + ni * 16 + (l & 15);
            const float bv = bias[gcol];
            #pragma unroll
            for (int q = 0; q < 4; ++q)
                g_gi[(size_t)(grow + q) * NG + gcol] = (_Float16)(acc[mi][ni][q] + bv);
        }
    }
}

// ---------------- phase 3: recurrence, whh AGPR-resident, 2 waves/SIMD ----------------
// r16 achieved full residency (WRITE_SIZE = out only) but at 1 wave/SIMD all
// latencies serialize -> 1.35 us/step with both pipes < 25%. This round: same
// scheme at 2 waves/SIMD. 128 WGs x 512 threads (8 waves); wave w owns cols
// [16w,16w+16) and [16w+128,16w+144) per gate -> 48 B-frags = 192 words/lane
// pinned AGPR; budget/lane = 256 = 192 AGPR + 64 arch (arch demand ~50).
// Duplicated-A trick: all 16 A rows hold h (broadcast ds_read), so all C rows
// are equal -> every lane group sel=l>>4 holds each tile's full output row in
// reg 0 -> lane l handles col j = (sel&1)*128 + 16w + (l&15); sel 2,3 lanes
// duplicate sel 0,1 (same values -> duplicate LDS/out writes are benign).
// Fully branchless step, ONE barrier, zero per-step weight memory traffic.
#define MF(A, B, C) __builtin_amdgcn_mfma_f32_16x16x32_f16((A), (B), (C), 0, 0, 0)

#define LDB1(NAME, CB, KT)                                                  \
    hfrag NAME;                                                             \
    _Pragma("unroll")                                                       \
    for (int e = 0; e < 8; ++e)                                             \
        NAME[e] = (_Float16)whhT[(size_t)((KT) * 32 + g8 + e) * NG + (CB) + c]; \
    asm("" : "+a"(NAME));

#define DECL8(P, CB)                                                        \
    LDB1(P##_0, CB, 0) LDB1(P##_1, CB, 1) LDB1(P##_2, CB, 2)                \
    LDB1(P##_3, CB, 3) LDB1(P##_4, CB, 4) LDB1(P##_5, CB, 5)                \
    LDB1(P##_6, CB, 6) LDB1(P##_7, CB, 7)

#define KST(KT)                                                             \
    {                                                                       \
        const hfrag A = *reinterpret_cast<const hfrag*>(hl + (KT) * 32 + g8); \
        aR0 = MF(A, BR0_##KT, aR0); aR1 = MF(A, BR1_##KT, aR1);             \
        aZ0 = MF(A, BZ0_##KT, aZ0); aZ1 = MF(A, BZ1_##KT, aZ1);             \
        aN0 = MF(A, BN0_##KT, aN0); aN1 = MF(A, BN1_##KT, aN1);             \
    }

__global__ void __launch_bounds__(512, 1) gru_rec_kernel(
    const float* __restrict__ h0, const float* __restrict__ whhT,
    float* __restrict__ out)
{
    __shared__ __align__(16) _Float16 hbuf[2][HH];   // 1 KB ping-pong h (f16)

    const int t   = threadIdx.x;
    const int b   = blockIdx.x;
    const int w   = t >> 6;             // wave 0..7
    const int l   = t & 63;
    const int c   = l & 15;             // col within tile
    const int sel = l >> 4;             // 0..3; sel&1 picks tile half
    const int g8  = sel * 8;            // k-sub-chunk base
    const int cw  = w * 16;
    // this lane's output column (sel 2,3 duplicate 0,1 -- benign)
    const int j   = (sel & 1) * 128 + cw + c;

    // --- 48 whh B-fragments, ALL pinned to AGPR ---
    DECL8(BR0, cw)        DECL8(BR1, 128 + cw)
    DECL8(BZ0, 256 + cw)  DECL8(BZ1, 384 + cw)
    DECL8(BN0, 512 + cw)  DECL8(BN1, 640 + cw)

    // --- init h ---
    float hp = h0[b * HH + j];
    hbuf[0][j] = (_Float16)hp;          // duplicate writes: same value
    __syncthreads();

    for (int ts = 0; ts < TT; ++ts) {
        const _Float16* hl  = hbuf[ts & 1];
        _Float16*       hn_ = hbuf[(ts & 1) ^ 1];

        // gi for this step (bias pre-folded; latency hides under MFMAs)
        const _Float16* gb = g_gi + ((size_t)ts * BB + b) * NG + j;
        const float gR = (float)gb[0];
        const float gZ = (float)gb[256];
        const float gN = (float)gb[512];

        f32x4 aR0 = {0.f,0.f,0.f,0.f}, aR1 = {0.f,0.f,0.f,0.f};
        f32x4 aZ0 = {0.f,0.f,0.f,0.f}, aZ1 = {0.f,0.f,0.f,0.f};
        f32x4 aN0 = {0.f,0.f,0.f,0.f}, aN1 = {0.f,0.f,0.f,0.f};
        KST(0) KST(1) KST(2) KST(3) KST(4) KST(5) KST(6) KST(7)

        // every lane's acc[0] = C row (sel*4) = C row 0 (duplicated A rows)
        const float sR = (sel & 1) ? aR1[0] : aR0[0];
        const float sZ = (sel & 1) ? aZ1[0] : aZ0[0];
        const float sN = (sel & 1) ? aN1[0] : aN0[0];

        const float r  = 1.f / (1.f + __expf(-(sR + gR)));
        const float z  = 1.f / (1.f + __expf(-(sZ + gZ)));
        const float e  = __expf(2.f * (gN + r * sN));   // tanh
        const float n  = 1.f - 2.f / (e + 1.f);
        const float hv = (1.f - z) * n + z * hp;

        hp = hv;
        hn_[j] = (_Float16)hv;          // duplicate writes: same value
        if (ts == TT - 1) out[b * HH + j] = hv;
        __syncthreads();
    }
}

extern "C" void kernel_launch(void* const* d_in, const int* in_sizes, int n_in,
                              void* d_out, int out_size, void* d_ws, size_t ws_size,
                              hipStream_t stream) {
    const float* x    = (const float*)d_in[0];
    const float* h0   = (const float*)d_in[1];
    const float* wihT = (const float*)d_in[2];
    const float* whhT = (const float*)d_in[3];
    const float* bias = (const float*)d_in[4];
    float*       out  = (float*)d_out;

    cvt_x_kernel<<<2048, 256, 0, stream>>>(x);
    cvt_wih_kernel<<<NG, 256, 0, stream>>>(wihT);
    gi_gemm_kernel<<<1024 * 6, 256, 0, stream>>>(bias);
    gru_rec_kernel<<<BB, 512, 0, stream>>>(h0, whhT, out);
}